// Round 1
// baseline (500.562 us; speedup 1.0000x reference)
//
#include <hip/hip_runtime.h>

#define MAT_N 256
#define MAT_ELEMS (MAT_N * MAT_N)
#define NUM_ITERS 20

// DPP quad-perm cross-lane adds (VALU pipe, no LDS traffic).
// 0xB1 = quad_perm [1,0,3,2] (lane ^ 1), 0x4E = quad_perm [2,3,0,1] (lane ^ 2)
__device__ __forceinline__ float dpp_xor1(float x) {
    int i = __builtin_bit_cast(int, x);
    int r = __builtin_amdgcn_update_dpp(i, i, 0xB1, 0xF, 0xF, true);
    return __builtin_bit_cast(float, r);
}
__device__ __forceinline__ float dpp_xor2(float x) {
    int i = __builtin_bit_cast(int, x);
    int r = __builtin_amdgcn_update_dpp(i, i, 0x4E, 0xF, 0xF, true);
    return __builtin_bit_cast(float, r);
}

// One 1024-thread block per 256x256 matrix.
// Thread (R = tid>>5, C = tid&31) owns q[i][j] = M[8R+i][C+32j].
__global__ __launch_bounds__(1024) void sinkhorn_kernel(
        const float* __restrict__ in, float* __restrict__ out) {
    const int tid = threadIdx.x;
    const int R = tid >> 5;   // 0..31 : rows 8R .. 8R+7
    const int C = tid & 31;   // 0..31 : cols C, C+32, ..., C+224

    const size_t base = (size_t)blockIdx.x * MAT_ELEMS;
    const float* __restrict__ src = in + base;
    float* __restrict__ dst = out + base;

    // LDS: all access patterns are bank-conflict-free by construction.
    __shared__ float P1[8][257];    // row partial sums: [colgroup][row]
    __shared__ float Q1[256][33];   // col partial sums: [col][rowgroup]
    __shared__ float Rr[256];       // row reciprocals
    __shared__ float Rc[256];       // col reciprocals

    float q[8][8];

    // ---- load + exp (linear-domain Sinkhorn) ----
    {
        const float* p = src + (8 * R) * MAT_N + C;
        #pragma unroll
        for (int i = 0; i < 8; ++i) {
            #pragma unroll
            for (int j = 0; j < 8; ++j) {
                q[i][j] = __expf(p[i * MAT_N + 32 * j]);
            }
        }
    }

    #pragma unroll 1
    for (int it = 0; it < NUM_ITERS; ++it) {
        // ================= ROW phase: M[r][*] /= rowsum =================
        float rs[8];
        #pragma unroll
        for (int i = 0; i < 8; ++i) {
            rs[i] = ((q[i][0] + q[i][1]) + (q[i][2] + q[i][3])) +
                    ((q[i][4] + q[i][5]) + (q[i][6] + q[i][7]));
        }
        // quad reduce across lanes C, C^1, C^2, C^3 (same rows, 4 colgroups)
        #pragma unroll
        for (int i = 0; i < 8; ++i) {
            rs[i] += dpp_xor1(rs[i]);
            rs[i] += dpp_xor2(rs[i]);
        }
        // each lane of the quad writes 2 of the 8 rows
        {
            const int cg  = C >> 2;        // 0..7
            const int sub = (C & 3) * 2;   // 0,2,4,6
            P1[cg][8 * R + sub]     = rs[sub];
            P1[cg][8 * R + sub + 1] = rs[sub + 1];
        }
        __syncthreads();

        if (tid < 256) {
            // sum 8 colgroup partials for row `tid` (lanes contiguous: conflict-free)
            float a = (P1[0][tid] + P1[1][tid]) + (P1[2][tid] + P1[3][tid]);
            float b = (P1[4][tid] + P1[5][tid]) + (P1[6][tid] + P1[7][tid]);
            Rr[tid] = 1.0f / (a + b);
        }
        __syncthreads();

        {
            float rr[8];
            #pragma unroll
            for (int i = 0; i < 8; ++i) rr[i] = Rr[8 * R + i];  // broadcast read
            #pragma unroll
            for (int i = 0; i < 8; ++i)
                #pragma unroll
                for (int j = 0; j < 8; ++j)
                    q[i][j] *= rr[i];
        }

        // ================= COL phase: M[*][c] /= colsum =================
        float cs[8];
        #pragma unroll
        for (int j = 0; j < 8; ++j) {
            cs[j] = ((q[0][j] + q[1][j]) + (q[2][j] + q[3][j])) +
                    ((q[4][j] + q[5][j]) + (q[6][j] + q[7][j]));
        }
        #pragma unroll
        for (int j = 0; j < 8; ++j) {
            Q1[C + 32 * j][R] = cs[j];   // bank = (C+R)%32 : conflict-free
        }
        __syncthreads();

        if (tid < 256) {
            float s0 = 0.f, s1 = 0.f, s2 = 0.f, s3 = 0.f;
            #pragma unroll
            for (int k = 0; k < 32; k += 4) {
                s0 += Q1[tid][k];
                s1 += Q1[tid][k + 1];
                s2 += Q1[tid][k + 2];
                s3 += Q1[tid][k + 3];
            }
            Rc[tid] = 1.0f / ((s0 + s1) + (s2 + s3));
        }
        __syncthreads();

        {
            float rc[8];
            #pragma unroll
            for (int j = 0; j < 8; ++j) rc[j] = Rc[C + 32 * j];  // coalesced read
            #pragma unroll
            for (int i = 0; i < 8; ++i)
                #pragma unroll
                for (int j = 0; j < 8; ++j)
                    q[i][j] *= rc[j];
        }
        __syncthreads();  // protect P1/Q1/Rr/Rc reuse next iteration
    }

    // ---- store ----
    {
        float* p = dst + (8 * R) * MAT_N + C;
        #pragma unroll
        for (int i = 0; i < 8; ++i) {
            #pragma unroll
            for (int j = 0; j < 8; ++j) {
                p[i * MAT_N + 32 * j] = q[i][j];
            }
        }
    }
}

extern "C" void kernel_launch(void* const* d_in, const int* in_sizes, int n_in,
                              void* d_out, int out_size, void* d_ws, size_t ws_size,
                              hipStream_t stream) {
    const float* in = (const float*)d_in[0];
    float* out = (float*)d_out;
    const int nmat = in_sizes[0] / MAT_ELEMS;  // 2048
    sinkhorn_kernel<<<nmat, 1024, 0, stream>>>(in, out);
}

// Round 2
// 386.764 us; speedup vs baseline: 1.2942x; 1.2942x over previous
//
#include <hip/hip_runtime.h>

#define MAT_N 256
#define MAT_ELEMS (MAT_N * MAT_N)
#define NUM_ITERS 20
#define NBLOCKS 256

// ---- cross-lane helpers -------------------------------------------------
// DPP ctrl: 0xB1 quad_perm[1,0,3,2] (xor1), 0x4E quad_perm[2,3,0,1] (xor2),
// 0x141 row_half_mirror (== xor4 once quads are uniform),
// 0x140 row_mirror (== xor8 once 8-groups are uniform).
template<int CTRL>
__device__ __forceinline__ float dpp_add(float x) {
    int i = __builtin_bit_cast(int, x);
    int r = __builtin_amdgcn_update_dpp(i, i, CTRL, 0xF, 0xF, true);
    return x + __builtin_bit_cast(float, r);
}
// ds_swizzle BitMode xor16 within 32-lane group: offset = (16<<10)|0x1F
__device__ __forceinline__ float swz16_add(float x) {
    int i = __builtin_bit_cast(int, x);
    int r = __builtin_amdgcn_ds_swizzle(i, 0x401F);
    return x + __builtin_bit_cast(float, r);
}
// Reduce across the 32 lanes of each wave half; result in every lane.
__device__ __forceinline__ float half32_reduce(float x) {
    x = dpp_add<0xB1>(x);
    x = dpp_add<0x4E>(x);
    x = dpp_add<0x141>(x);
    x = dpp_add<0x140>(x);
    x = swz16_add(x);
    return x;
}

// One 1024-thread persistent block; processes nmat/gridDim.x matrices.
// Thread (R=tid>>5, C=tid&31) owns rows 8R..8R+7, cols {4C..4C+3, 128+4C..128+4C+3}.
// q[i][j]: j 0..3 -> col 4C+j ; j 4..7 -> col 128+4C+(j-4).
__global__ __launch_bounds__(1024, 4) void sinkhorn_kernel(
        const float* __restrict__ in, float* __restrict__ out, int nmat) {
    const int tid = threadIdx.x;
    const int R = tid >> 5;   // 0..31 (half-wave index)
    const int C = tid & 31;

    // Col-phase partials: Q1[R][col], stride 260 (16B-aligned rows, staggered banks)
    __shared__ __align__(16) float Q1[32][260];     // 33280 B
    __shared__ __align__(16) float Vc[256];         //  1024 B
    __shared__ __align__(16) float4 PREF[7][1024];  // 114688 B  (next-matrix chunks 6..12)

    const int mpb = nmat / gridDim.x;   // 8
    const int m0 = blockIdx.x * mpb;

    float q[8][8];
    float4 pr0, pr1, pr2, pr3, pr4, pr5;  // next-matrix chunks 0..5
    float4 hold;                          // LDS-prefetch staging (1-iter delay)

    #pragma unroll 1
    for (int mi = 0; mi < mpb; ++mi) {
        const float4* __restrict__ cur4 = (const float4*)(in + (size_t)(m0 + mi) * MAT_ELEMS);
        const float4* __restrict__ nxt4 = (const float4*)(in + (size_t)(m0 + mi + 1) * MAT_ELEMS);
        const bool has_next = (mi + 1 < mpb);

        // ---------------- build q = exp(P0) ----------------
        if (mi == 0) {
            #pragma unroll
            for (int c = 0; c < 16; ++c) {
                const int i = c & 7, d = c >> 3;
                float4 t = cur4[(8 * R + i) * 64 + C + 32 * d];
                q[i][4 * d + 0] = __expf(t.x); q[i][4 * d + 1] = __expf(t.y);
                q[i][4 * d + 2] = __expf(t.z); q[i][4 * d + 3] = __expf(t.w);
            }
        } else {
            // register chunks 0..5 -> q[0..5][0..3]
            q[0][0]=__expf(pr0.x); q[0][1]=__expf(pr0.y); q[0][2]=__expf(pr0.z); q[0][3]=__expf(pr0.w);
            q[1][0]=__expf(pr1.x); q[1][1]=__expf(pr1.y); q[1][2]=__expf(pr1.z); q[1][3]=__expf(pr1.w);
            q[2][0]=__expf(pr2.x); q[2][1]=__expf(pr2.y); q[2][2]=__expf(pr2.z); q[2][3]=__expf(pr2.w);
            q[3][0]=__expf(pr3.x); q[3][1]=__expf(pr3.y); q[3][2]=__expf(pr3.z); q[3][3]=__expf(pr3.w);
            q[4][0]=__expf(pr4.x); q[4][1]=__expf(pr4.y); q[4][2]=__expf(pr4.z); q[4][3]=__expf(pr4.w);
            q[5][0]=__expf(pr5.x); q[5][1]=__expf(pr5.y); q[5][2]=__expf(pr5.z); q[5][3]=__expf(pr5.w);
            // LDS chunks 6..12 (thread-private slots, written by this thread last matrix)
            #pragma unroll
            for (int k = 0; k < 7; ++k) {
                const int c = 6 + k, i = c & 7, d = c >> 3;
                float4 t = PREF[k][tid];
                q[i][4 * d + 0] = __expf(t.x); q[i][4 * d + 1] = __expf(t.y);
                q[i][4 * d + 2] = __expf(t.z); q[i][4 * d + 3] = __expf(t.w);
            }
            // direct chunks 13..15
            #pragma unroll
            for (int c = 13; c < 16; ++c) {
                const int i = c & 7, d = c >> 3;
                float4 t = cur4[(8 * R + i) * 64 + C + 32 * d];
                q[i][4 * d + 0] = __expf(t.x); q[i][4 * d + 1] = __expf(t.y);
                q[i][4 * d + 2] = __expf(t.z); q[i][4 * d + 3] = __expf(t.w);
            }
        }

        float vc[8];
        #pragma unroll
        for (int j = 0; j < 8; ++j) vc[j] = 1.0f;
        float u[8];

        #pragma unroll 1
        for (int it = 0; it < NUM_ITERS; ++it) {
            // ---- prefetch next matrix (spread over iterations) ----
            if (has_next) {
                if (it >= 1 && it <= 7) PREF[it - 1][tid] = hold;  // write last iter's load
                if (it < 7) {
                    const int c = 6 + it, i = c & 7, d = c >> 3;
                    hold = nxt4[(8 * R + i) * 64 + C + 32 * d];
                }
                if (it == 8)  pr0 = nxt4[(8 * R + 0) * 64 + C];
                if (it == 9)  pr1 = nxt4[(8 * R + 1) * 64 + C];
                if (it == 10) pr2 = nxt4[(8 * R + 2) * 64 + C];
                if (it == 11) pr3 = nxt4[(8 * R + 3) * 64 + C];
                if (it == 12) pr4 = nxt4[(8 * R + 4) * 64 + C];
                if (it == 13) pr5 = nxt4[(8 * R + 5) * 64 + C];
            }

            // ---- row phase: u = 1 / (M v), fully in-wave ----
            #pragma unroll
            for (int i = 0; i < 8; ++i) {
                float s = q[i][0] * vc[0];
                #pragma unroll
                for (int j = 1; j < 8; ++j) s = fmaf(q[i][j], vc[j], s);
                s = half32_reduce(s);          // sum over the 32 lanes sharing R
                u[i] = __builtin_amdgcn_rcpf(s);
            }

            // ---- col phase: v = 1 / (M^T u) ----
            float cs[8];
            #pragma unroll
            for (int j = 0; j < 8; ++j) {
                float s = q[0][j] * u[0];
                #pragma unroll
                for (int i = 1; i < 8; ++i) s = fmaf(q[i][j], u[i], s);
                cs[j] = s;
            }
            *(float4*)&Q1[R][4 * C]       = make_float4(cs[0], cs[1], cs[2], cs[3]);
            *(float4*)&Q1[R][4 * C + 128] = make_float4(cs[4], cs[5], cs[6], cs[7]);
            __syncthreads();

            if (tid < 512) {                    // 2 threads per column
                const int col = tid >> 1;
                const int s0 = (tid & 1) * 16;
                float a0 = 0.f, a1 = 0.f, a2 = 0.f, a3 = 0.f;
                #pragma unroll
                for (int s = 0; s < 16; s += 4) {
                    a0 += Q1[s0 + s + 0][col];
                    a1 += Q1[s0 + s + 1][col];
                    a2 += Q1[s0 + s + 2][col];
                    a3 += Q1[s0 + s + 3][col];
                }
                float t = (a0 + a1) + (a2 + a3);
                t = dpp_add<0xB1>(t);           // combine the pair (lane^1)
                if ((tid & 1) == 0) Vc[col] = __builtin_amdgcn_rcpf(t);
            }
            __syncthreads();

            {
                float4 a = *(const float4*)&Vc[4 * C];
                float4 b = *(const float4*)&Vc[4 * C + 128];
                vc[0] = a.x; vc[1] = a.y; vc[2] = a.z; vc[3] = a.w;
                vc[4] = b.x; vc[5] = b.y; vc[6] = b.z; vc[7] = b.w;
            }
        }

        // ---------------- store: out = u_i * q * v_j ----------------
        float4* out4 = (float4*)(out + (size_t)(m0 + mi) * MAT_ELEMS);
        #pragma unroll
        for (int i = 0; i < 8; ++i) {
            const float s = u[i];
            float4 o0 = make_float4(q[i][0] * vc[0] * s, q[i][1] * vc[1] * s,
                                    q[i][2] * vc[2] * s, q[i][3] * vc[3] * s);
            float4 o1 = make_float4(q[i][4] * vc[4] * s, q[i][5] * vc[5] * s,
                                    q[i][6] * vc[6] * s, q[i][7] * vc[7] * s);
            out4[(8 * R + i) * 64 + C]      = o0;
            out4[(8 * R + i) * 64 + C + 32] = o1;
        }
    }
}

extern "C" void kernel_launch(void* const* d_in, const int* in_sizes, int n_in,
                              void* d_out, int out_size, void* d_ws, size_t ws_size,
                              hipStream_t stream) {
    const float* in = (const float*)d_in[0];
    float* out = (float*)d_out;
    const int nmat = in_sizes[0] / MAT_ELEMS;  // 2048
    sinkhorn_kernel<<<NBLOCKS, 1024, 0, stream>>>(in, out, nmat);
}